// Round 8
// baseline (1511.552 us; speedup 1.0000x reference)
//
#include <hip/hip_runtime.h>

// FeatureTokenizer — R8: block-contiguous stores + scatter-fill probe.
//
// Theory: all R1-R7 variants wrote 1-KiB wave granules scattered MBs apart
// (grid-stride). Pure-store probe at that geometry hit only 4.26 TB/s while
// rocclr's fill (dense sequential chunks) sustains 6.5 TB/s. Suspect: write
// address locality (L2 writeback / HBM row-buffer fragmentation).
//
// Main kernel: 1024 blocks x 256 threads; block k owns the contiguous
// 1 MiB chunk [k*65536, (k+1)*65536) of fx4 slots, written in sequential
// 4-KiB steps (256 lanes x 16 B). W/b reads are no longer hoistable but are
// L2-resident (128 KB hot set); x/m are 2 broadcast dwords per wave-iter.
//
// Probe: pure-store fill into d_ws with the OLD scatter geometry (524288
// threads, 16B/thread, 8MB-apart granules), 2 passes so it ranks in top-5.

typedef float fx4 __attribute__((ext_vector_type(4)));

constexpr int kC = 128;
constexpr int kH4 = 32;                        // float4 per H-row
constexpr int kTotal4 = 1 << 26;               // 67,108,864 fx4 outputs
constexpr int kBlock = 256;

// --- main kernel geometry ---
constexpr int kGridMain = 1024;                // 4 blocks/CU, 16 waves/CU
constexpr int kChunk4 = kTotal4 / kGridMain;   // 65536 fx4 = 1 MiB
constexpr int kItersMain = kChunk4 / kBlock;   // 256

__global__ __launch_bounds__(kBlock) void FeatureTokenizer_69664369541889_kernel(
    const float* __restrict__ x,      // (B, C)
    const float* __restrict__ m,      // (B, C)
    const float* __restrict__ W,      // (C, H)
    const float* __restrict__ bias,   // (C, H)
    const float* __restrict__ me,     // (1, H)
    float* __restrict__ out)          // (B, C, H)
{
    const fx4* __restrict__ W4  = reinterpret_cast<const fx4*>(W);
    const fx4* __restrict__ b4  = reinterpret_cast<const fx4*>(bias);
    const fx4* __restrict__ me4 = reinterpret_cast<const fx4*>(me);
    fx4* __restrict__ out4      = reinterpret_cast<fx4*>(out);

    const int tid  = threadIdx.x;
    const int h4   = tid & (kH4 - 1);          // fixed per thread
    const fx4 e    = me4[h4];                  // hoisted

    int idx = blockIdx.x * kChunk4 + tid;      // sequential within chunk
    int rc  = (blockIdx.x * kChunk4) >> 5;     // row of lane group
    rc += (tid >> 5);                          // lanes 0-31: rc, 32-63: rc+1 ... 224-255: rc+7

#pragma unroll 8
    for (int i = 0; i < kItersMain; ++i) {
        const int cc = rc & (kC - 1);
        const fx4 w  = W4[cc * kH4 + h4];      // 512B coalesced per 32-lane group, L2-hot
        const fx4 bb = b4[cc * kH4 + h4];
        const float xv = x[rc];                // broadcast dword
        const float mv = m[rc];
        const float om = 1.0f - mv;

        fx4 o;
        o.x = fmaf(fmaf(xv, w.x, bb.x), om, e.x * mv);
        o.y = fmaf(fmaf(xv, w.y, bb.y), om, e.y * mv);
        o.z = fmaf(fmaf(xv, w.z, bb.z), om, e.z * mv);
        o.w = fmaf(fmaf(xv, w.w, bb.w), om, e.w * mv);

        out4[idx] = o;                         // 4-KiB sequential steps per block
        idx += kBlock;
        rc  += kBlock >> 5;                    // +8 rows
    }
}

// --- probe: pure-store fill, OLD scatter geometry, into d_ws ---
constexpr int kGridP = 2048;
constexpr long long kStrideP = (long long)kGridP * kBlock;   // 524288 fx4 = 8 MiB

__global__ __launch_bounds__(kBlock) void ws_scatter_fill_probe(
    fx4* __restrict__ ws, long long n4)
{
    fx4 v;
    v.x = 1.0f; v.y = 2.0f; v.z = 3.0f; v.w = 4.0f;
    const long long t0 = (long long)blockIdx.x * kBlock + threadIdx.x;
    for (int pass = 0; pass < 2; ++pass) {
        for (long long idx = t0; idx < n4; idx += kStrideP) {
            ws[idx] = v;
        }
    }
}

extern "C" void kernel_launch(void* const* d_in, const int* in_sizes, int n_in,
                              void* d_out, int out_size, void* d_ws, size_t ws_size,
                              hipStream_t stream) {
    const float* x    = (const float*)d_in[0];  // x_numerical (B, C)
    const float* m    = (const float*)d_in[1];  // mask (B, C)
    const float* W    = (const float*)d_in[2];  // W (C, H)
    const float* bias = (const float*)d_in[3];  // b (C, H)
    const float* me   = (const float*)d_in[4];  // mask_embedding (1, H)
    float* out        = (float*)d_out;

    FeatureTokenizer_69664369541889_kernel<<<kGridMain, kBlock, 0, stream>>>(
        x, m, W, bias, me, out);

    long long n4 = (long long)(ws_size / 16);
    const long long cap = 3LL * (long long)kTotal4;   // <= 3 GiB of fx4
    if (n4 > cap) n4 = cap;
    if (n4 > 0) {
        ws_scatter_fill_probe<<<kGridP, kBlock, 0, stream>>>((fx4*)d_ws, n4);
    }
}

// Round 9
// 1126.391 us; speedup vs baseline: 1.3419x; 1.3419x over previous
//
#include <hip/hip_runtime.h>

// FeatureTokenizer — R9: fill-mimicking dense sweep (huge grid, 1 store/thread)
// + dense pure-store probe.
//
// Evidence so far: rocclr fill = 6.5 TB/s (dense dispatch-ordered sweep of the
// whole 4.3 GB allocation, short-lived waves). Our scatter pure-store = 5.2;
// scatter+loads = 4.26-4.7; block-chunk streams = 4.0. Theory: write BW is
// maximized when the ACTIVE write window is a compact front sliding in
// dispatch order (row-buffer + L2 writeback locality), i.e. one store per
// short-lived thread, huge grid.

typedef float fx4 __attribute__((ext_vector_type(4)));

constexpr int kC = 128;
constexpr int kH4 = 32;                        // fx4 per H-row
constexpr int kTotal4 = 1 << 26;               // 67,108,864 fx4 outputs
constexpr int kBlock = 256;
constexpr int kGridMain = kTotal4 / kBlock;    // 262,144 workgroups

__global__ __launch_bounds__(kBlock) void FeatureTokenizer_69664369541889_kernel(
    const float* __restrict__ x,      // (B, C)
    const float* __restrict__ m,      // (B, C)
    const float* __restrict__ W,      // (C, H)
    const float* __restrict__ bias,   // (C, H)
    const float* __restrict__ me,     // (1, H)
    float* __restrict__ out)          // (B, C, H)
{
    const fx4* __restrict__ W4  = reinterpret_cast<const fx4*>(W);
    const fx4* __restrict__ b4  = reinterpret_cast<const fx4*>(bias);
    const fx4* __restrict__ me4 = reinterpret_cast<const fx4*>(me);
    fx4* __restrict__ out4      = reinterpret_cast<fx4*>(out);

    const int t  = blockIdx.x * kBlock + threadIdx.x;  // < 2^26
    const int h4 = t & (kH4 - 1);
    const int rc = t >> 5;                             // 32 lanes share a row
    const int cc = rc & (kC - 1);

    const float xv = x[rc];                 // broadcast dword (L2-served)
    const float mv = m[rc];
    const fx4 w  = W4[cc * kH4 + h4];       // 512B/group, L1/L2-hot (64KB table)
    const fx4 bb = b4[cc * kH4 + h4];
    const fx4 e  = me4[h4];
    const float om = 1.0f - mv;

    fx4 o;
    o.x = fmaf(fmaf(xv, w.x, bb.x), om, e.x * mv);
    o.y = fmaf(fmaf(xv, w.y, bb.y), om, e.y * mv);
    o.z = fmaf(fmaf(xv, w.z, bb.z), om, e.z * mv);
    o.w = fmaf(fmaf(xv, w.w, bb.w), om, e.w * mv);

    out4[t] = o;                            // one coalesced 4KB store per wave-instr
}

// Probe: pure-store dense sweep into d_ws. Block k fills 2 consecutive
// fully-coalesced 4KB segments (512 fx4). 6.44 GB -> ~990us, ranks in top-5.
__global__ __launch_bounds__(kBlock) void ws_dense_fill_probe(
    fx4* __restrict__ ws, long long n4)
{
    fx4 v;
    v.x = 1.0f; v.y = 2.0f; v.z = 3.0f; v.w = 4.0f;
    const long long i0 = (long long)blockIdx.x * 512 + threadIdx.x;
    if (i0 + 256 < n4) {
        ws[i0]       = v;
        ws[i0 + 256] = v;
    }
}

extern "C" void kernel_launch(void* const* d_in, const int* in_sizes, int n_in,
                              void* d_out, int out_size, void* d_ws, size_t ws_size,
                              hipStream_t stream) {
    const float* x    = (const float*)d_in[0];  // x_numerical (B, C)
    const float* m    = (const float*)d_in[1];  // mask (B, C)
    const float* W    = (const float*)d_in[2];  // W (C, H)
    const float* bias = (const float*)d_in[3];  // b (C, H)
    const float* me   = (const float*)d_in[4];  // mask_embedding (1, H)
    float* out        = (float*)d_out;

    FeatureTokenizer_69664369541889_kernel<<<kGridMain, kBlock, 0, stream>>>(
        x, m, W, bias, me, out);

    // Dense probe over ws, twice (6.44 GB total) to rank in the top-5.
    long long n4 = (long long)(ws_size / 16);
    const long long cap = 3LL << 27;           // 3 GiB of fx4
    if (n4 > cap) n4 = cap;
    if (n4 >= 512) {
        const int gridP = (int)(n4 / 512);
        ws_dense_fill_probe<<<gridP * 2, kBlock, 0, stream>>>((fx4*)d_ws,
            n4);  // blocks >= n4/512 wrap via bounds check? no — see below
    }
}

// NOTE on probe sizing: gridP*2 blocks, but blocks with i0+256 >= n4 exit
// immediately; to get 2 full passes we instead rely on launching gridP*2
// where the second half re-covers the same range:
//   block b >= gridP maps to (b - gridP) via the modulo below.
// (Implemented via a wrapper kernel attribute-free trick is overkill; the
// bounds check above means only gridP blocks write. To still exceed 650us
// in top-5 we accept a single 3.22GB pass at ~500us if 6.5 TB/s; if the
// probe misses top-5, the main kernel's time = total - ~500us is still a
// clean read.)

// Round 10
// 240.533 us; speedup vs baseline: 6.2842x; 4.6829x over previous
//
#include <hip/hip_runtime.h>

// FeatureTokenizer — R10: R4 geometry + explicit load/store software pipeline.
//
// Measured HIP store ceilings on this box (R8/R9 probes): scatter 5.2 TB/s,
// dense 5.0 TB/s -> pure-store ceiling ~5.0-5.2 TB/s; rocclr fill's 6.5 is
// not HIP-reproducible. Roofline: 1.074 GB / 5.2 TB/s ~= 207 us. R4 = 233.
//
// Remaining theory: in-order vmcnt makes each unrolled group's load-wait
// retire the PREVIOUS group's 8 stores (loads were emitted after them), so
// every group stalls on store-queue drain. Fix: prefetch next group's x/m
// pairs into registers BEFORE this group's stores issue, so the load-wait
// is independent of the congested store stream.

typedef float fx4 __attribute__((ext_vector_type(4)));

constexpr int kC = 128;
constexpr int kH4 = 32;                        // fx4 per (b,c) row
constexpr int kTotal4 = 1 << 26;               // 67,108,864 fx4 outputs
constexpr int kBlock = 256;
constexpr int kGrid = 2048;
constexpr int kStride4 = kGrid * kBlock;       // 524288 fx4
constexpr int kIters = kTotal4 / kStride4;     // 128 (exact)
constexpr int kRcStep = kStride4 / kH4;        // 16384 rows (== 0 mod kC)
constexpr int kGroup = 8;
constexpr int kGroups = kIters / kGroup;       // 16

__global__ __launch_bounds__(kBlock) void FeatureTokenizer_69664369541889_kernel(
    const float* __restrict__ x,      // (B, C)
    const float* __restrict__ m,      // (B, C)
    const float* __restrict__ W,      // (C, H)
    const float* __restrict__ bias,   // (C, H)
    const float* __restrict__ me,     // (1, H)
    float* __restrict__ out)          // (B, C, H)
{
    const fx4* __restrict__ W4  = reinterpret_cast<const fx4*>(W);
    const fx4* __restrict__ b4  = reinterpret_cast<const fx4*>(bias);
    const fx4* __restrict__ me4 = reinterpret_cast<const fx4*>(me);
    fx4* __restrict__ out4      = reinterpret_cast<fx4*>(out);

    const int idx0 = blockIdx.x * kBlock + threadIdx.x;   // [0, 524288)
    const int h4   = idx0 & (kH4 - 1);
    const int rc0  = idx0 >> 5;
    const int cc   = rc0 & (kC - 1);              // loop-invariant

    const fx4 w  = W4[cc * kH4 + h4];             // hoisted, L2-hot
    const fx4 bb = b4[cc * kH4 + h4];
    const fx4 e  = me4[h4];

    // Pipeline registers: current and next group of 8 (x, m) pairs.
    float xc[kGroup], mc[kGroup];
    int rcl = rc0;
#pragma unroll
    for (int j = 0; j < kGroup; ++j) {            // prologue loads
        xc[j] = x[rcl]; mc[j] = m[rcl]; rcl += kRcStep;
    }

    int oidx = idx0;
    for (int g = 0; g < kGroups; ++g) {
        float xn[kGroup], mn[kGroup];
        const bool more = (g + 1 < kGroups);      // uniform branch
        if (more) {
#pragma unroll
            for (int j = 0; j < kGroup; ++j) {    // issue next loads EARLY,
                xn[j] = x[rcl]; mn[j] = m[rcl];   // before any store below
                rcl += kRcStep;
            }
        }
#pragma unroll
        for (int j = 0; j < kGroup; ++j) {
            const float om = 1.0f - mc[j];
            fx4 o;
            o.x = fmaf(fmaf(xc[j], w.x, bb.x), om, e.x * mc[j]);
            o.y = fmaf(fmaf(xc[j], w.y, bb.y), om, e.y * mc[j]);
            o.z = fmaf(fmaf(xc[j], w.z, bb.z), om, e.z * mc[j]);
            o.w = fmaf(fmaf(xc[j], w.w, bb.w), om, e.w * mc[j]);
            out4[oidx] = o;
            oidx += kStride4;
        }
        if (more) {
#pragma unroll
            for (int j = 0; j < kGroup; ++j) { xc[j] = xn[j]; mc[j] = mn[j]; }
        }
    }
}

extern "C" void kernel_launch(void* const* d_in, const int* in_sizes, int n_in,
                              void* d_out, int out_size, void* d_ws, size_t ws_size,
                              hipStream_t stream) {
    const float* x    = (const float*)d_in[0];  // x_numerical (B, C)
    const float* m    = (const float*)d_in[1];  // mask (B, C)
    const float* W    = (const float*)d_in[2];  // W (C, H)
    const float* bias = (const float*)d_in[3];  // b (C, H)
    const float* me   = (const float*)d_in[4];  // mask_embedding (1, H)
    float* out        = (float*)d_out;

    FeatureTokenizer_69664369541889_kernel<<<kGrid, kBlock, 0, stream>>>(
        x, m, W, bias, me, out);
}

// Round 11
// 192.698 us; speedup vs baseline: 7.8441x; 1.2482x over previous
//
#include <hip/hip_runtime.h>

// FeatureTokenizer — R11: R4 + explicit streaming store policy (sc1 nt).
//
// Ceiling evidence: rocclr fill 6.5 TB/s; HIP pure-store probes 5.0-5.2;
// R4 4.67 eff. All geometry/concurrency/pipeline levers tested & dead.
// Last untested mechanism: store cache-policy bits. The builtin NT store
// (R3) emits only `nt`; here we emit `global_store_dwordx4 ... sc1 nt`
// (device-scope + non-temporal = streaming write, minimal L2 retention /
// writeback double-handling). Everything else is byte-identical to R4
// (233.4 us) for a clean A/B.

typedef float fx4 __attribute__((ext_vector_type(4)));

constexpr int kC = 128;
constexpr int kH4 = 32;                        // fx4 per (b,c) row
constexpr int kTotal4 = 1 << 26;               // 67,108,864 fx4 outputs
constexpr int kBlock = 256;
constexpr int kGrid = 2048;
constexpr int kStride4 = kGrid * kBlock;       // 524288 fx4
constexpr int kIters = kTotal4 / kStride4;     // 128 (exact)
constexpr int kRcStep = kStride4 / kH4;        // 16384 rows (== 0 mod kC)

__global__ __launch_bounds__(kBlock) void FeatureTokenizer_69664369541889_kernel(
    const float* __restrict__ x,      // (B, C)
    const float* __restrict__ m,      // (B, C)
    const float* __restrict__ W,      // (C, H)
    const float* __restrict__ bias,   // (C, H)
    const float* __restrict__ me,     // (1, H)
    float* __restrict__ out)          // (B, C, H)
{
    const fx4* __restrict__ W4  = reinterpret_cast<const fx4*>(W);
    const fx4* __restrict__ b4  = reinterpret_cast<const fx4*>(bias);
    const fx4* __restrict__ me4 = reinterpret_cast<const fx4*>(me);
    fx4* __restrict__ out4      = reinterpret_cast<fx4*>(out);

    const int idx0 = blockIdx.x * kBlock + threadIdx.x;   // [0, 524288)
    const int h4   = idx0 & (kH4 - 1);
    int rc         = idx0 >> 5;                           // [0, 16384)
    const int cc   = rc & (kC - 1);                       // fixed per thread

    // Loop-invariant per-thread tables (L2-resident).
    const fx4 w  = W4[cc * kH4 + h4];
    const fx4 bb = b4[cc * kH4 + h4];
    const fx4 e  = me4[h4];

    int oidx = idx0;
#pragma unroll 8
    for (int it = 0; it < kIters; ++it) {
        const float xv = x[rc];       // 32 lanes broadcast same dword
        const float mv = m[rc];
        const float om = 1.0f - mv;

        fx4 o;
        o.x = fmaf(fmaf(xv, w.x, bb.x), om, e.x * mv);
        o.y = fmaf(fmaf(xv, w.y, bb.y), om, e.y * mv);
        o.z = fmaf(fmaf(xv, w.z, bb.z), om, e.z * mv);
        o.w = fmaf(fmaf(xv, w.w, bb.w), om, e.w * mv);

        // Streaming store: device-scope, non-temporal. No "memory" clobber
        // (out is never read in-kernel) so the compiler keeps scheduling
        // freedom for the x/m loads; volatile preserves emission & order.
        fx4* p = &out4[oidx];
        asm volatile("global_store_dwordx4 %0, %1, off sc1 nt"
                     :: "v"(p), "v"(o));

        rc   += kRcStep;
        oidx += kStride4;
    }
}

extern "C" void kernel_launch(void* const* d_in, const int* in_sizes, int n_in,
                              void* d_out, int out_size, void* d_ws, size_t ws_size,
                              hipStream_t stream) {
    const float* x    = (const float*)d_in[0];  // x_numerical (B, C)
    const float* m    = (const float*)d_in[1];  // mask (B, C)
    const float* W    = (const float*)d_in[2];  // W (C, H)
    const float* bias = (const float*)d_in[3];  // b (C, H)
    const float* me   = (const float*)d_in[4];  // mask_embedding (1, H)
    float* out        = (float*)d_out;

    FeatureTokenizer_69664369541889_kernel<<<kGrid, kBlock, 0, stream>>>(
        x, m, W, bias, me, out);
}